// Round 3
// baseline (111.648 us; speedup 1.0000x reference)
//
#include <hip/hip_runtime.h>
#include <math.h>

// Problem constants (fixed by setup_inputs).
#define CC 4
#define NN 4096                  // vertices per class
#define MM 4096                  // queries per class
#define DD 32
#define GR 16                    // grid resolution per axis
#define NCELL (GR * GR * GR)     // 4096 cells per class
#define LPQ 16                   // lanes cooperating per query
#define BLOCK 256

// ws layout (bytes):
//   cursor/counts u32[CC*NCELL]      @ 0          (65536)
//   starts        u32[CC*(NCELL+1)]  @ 65536      (65552)
//   sorted        float4[CC*NN]      @ 131088     (262144)  -- 16B aligned
#define WS_STARTS 65536
#define WS_SORTED 131088

__device__ __forceinline__ int cellof(float x) {
    int c = (int)(x * (float)GR);
    return min(max(c, 0), GR - 1);
}

// Branchless sorted-insert of (d, j) into top-3 (d0<=d1<=d2). Strict <
// keeps earlier entries on ties.
__device__ __forceinline__ void ins3b(float d, int j,
                                      float& d0, float& d1, float& d2,
                                      int& i0, int& i1, int& i2) {
    bool l2 = d < d2, l1 = d < d1, l0 = d < d0;
    d2 = l1 ? d1 : (l2 ? d : d2);
    i2 = l1 ? i1 : (l2 ? j : i2);
    d1 = l0 ? d0 : (l1 ? d : d1);
    i1 = l0 ? i0 : (l1 ? j : i1);
    d0 = l0 ? d : d0;
    i0 = l0 ? j : i0;
}

__global__ __launch_bounds__(BLOCK) void k_zero(unsigned* __restrict__ counts) {
    counts[blockIdx.x * BLOCK + threadIdx.x] = 0u;   // grid == CC*NCELL/BLOCK
}

__global__ __launch_bounds__(BLOCK) void k_count(const float* __restrict__ verts,
                                                 unsigned* __restrict__ counts) {
    const int i = blockIdx.x * BLOCK + threadIdx.x;  // 0..CC*NN-1
    const int c = i >> 12;
    const float x = verts[3 * i], y = verts[3 * i + 1], z = verts[3 * i + 2];
    const int cell = (cellof(x) * GR + cellof(y)) * GR + cellof(z);
    atomicAdd(&counts[c * NCELL + cell], 1u);
}

// One block per class: exclusive prefix over 4096 cell counts.
// Writes starts[] and overwrites counts[] with the same values (scatter cursor).
__global__ __launch_bounds__(BLOCK) void k_scan(unsigned* __restrict__ counts,
                                                unsigned* __restrict__ starts) {
    const int c = blockIdx.x;
    const int tid = threadIdx.x;
    unsigned* cnt = counts + c * NCELL;
    unsigned* st  = starts + c * (NCELL + 1);

    unsigned local[16];
    unsigned sum = 0;
    #pragma unroll
    for (int k = 0; k < 16; ++k) { local[k] = cnt[tid * 16 + k]; sum += local[k]; }

    // Inclusive wave scan of per-thread sums.
    unsigned incl = sum;
    #pragma unroll
    for (int off = 1; off < 64; off <<= 1) {
        unsigned v = __shfl_up(incl, off);
        if ((tid & 63) >= off) incl += v;
    }
    __shared__ unsigned wsum[4];
    const int wid = tid >> 6;
    if ((tid & 63) == 63) wsum[wid] = incl;
    __syncthreads();
    unsigned wbase = 0;
    for (int w = 0; w < wid; ++w) wbase += wsum[w];

    unsigned base = wbase + incl - sum;  // exclusive prefix for this thread
    #pragma unroll
    for (int k = 0; k < 16; ++k) {
        st[tid * 16 + k]  = base;
        cnt[tid * 16 + k] = base;        // cursor copy
        base += local[k];
    }
    if (tid == BLOCK - 1) st[NCELL] = base;   // == NN
}

__global__ __launch_bounds__(BLOCK) void k_scatter(const float* __restrict__ verts,
                                                   unsigned* __restrict__ cursor,
                                                   float4* __restrict__ sorted) {
    const int i = blockIdx.x * BLOCK + threadIdx.x;
    const int c = i >> 12;
    const int li = i & (NN - 1);
    const float x = verts[3 * i], y = verts[3 * i + 1], z = verts[3 * i + 2];
    const int cell = (cellof(x) * GR + cellof(y)) * GR + cellof(z);
    const unsigned pos = atomicAdd(&cursor[c * NCELL + cell], 1u);
    float4 p;
    p.x = x; p.y = y; p.z = z; p.w = __int_as_float(li);
    sorted[c * NN + pos] = p;
}

__global__ __launch_bounds__(BLOCK) void k_query(
    const float* __restrict__ feat,       // [CC*NN, DD]
    const float* __restrict__ nverts,     // [CC, MM, 3] flat
    const unsigned* __restrict__ starts,  // [CC][NCELL+1]
    const float4* __restrict__ sorted,    // [CC][NN]
    float* __restrict__ out)              // [CC*MM, DD]
{
    const int tid = threadIdx.x;
    const int t = tid & (LPQ - 1);              // lane within query group
    const int g = tid >> 4;                     // query slot in block
    const int mg = blockIdx.x * (BLOCK / LPQ) + g;   // global query 0..16383
    const int c = mg >> 12;

    const float qx = nverts[3 * mg + 0];
    const float qy = nverts[3 * mg + 1];
    const float qz = nverts[3 * mg + 2];

    const unsigned* st = starts + c * (NCELL + 1);
    const float4* pts = sorted + (size_t)c * NN;

    const int cx = cellof(qx), cy = cellof(qy), cz = cellof(qz);

    // Seeds: the off-block 1.0 entries (local idx = global - c*NN) so the
    // degenerate "fewer than 3 in-block dists < 1.0" case matches jax ties.
    const int offb = (c == 0) ? NN : (-c * NN);

    float d0, d1, d2;
    int   i0, i1, i2;
    const float cs = 1.0f / (float)GR;

    int r = 2;
    for (;;) {
        d0 = d1 = d2 = 1.0f;
        i0 = offb; i1 = offb + 1; i2 = offb + 2;

        const int lx = max(cx - r, 0), hx = min(cx + r, GR - 1);
        const int ly = max(cy - r, 0), hy = min(cy + r, GR - 1);
        const int lz = max(cz - r, 0), hz = min(cz + r, GR - 1);

        // Distribute (px,py) column-runs round-robin over the 16 lanes.
        int p = 0;
        for (int px = lx; px <= hx; ++px) {
            for (int py = ly; py <= hy; ++py) {
                if ((p & (LPQ - 1)) == t) {
                    const int rb = (px * GR + py) * GR;
                    const unsigned a = st[rb + lz];
                    const unsigned b = st[rb + hz + 1];
                    for (unsigned s = a; s < b; s += 2) {
                        float4 p0 = pts[s];
                        float4 p1 = (s + 1 < b) ? pts[s + 1]
                                                : make_float4(9e9f, 9e9f, 9e9f, 0.0f);
                        float dx0 = p0.x - qx, dy0 = p0.y - qy, dz0 = p0.z - qz;
                        float dd0 = fmaf(dx0, dx0, fmaf(dy0, dy0, dz0 * dz0));
                        ins3b(dd0, __float_as_int(p0.w), d0, d1, d2, i0, i1, i2);
                        float dx1 = p1.x - qx, dy1 = p1.y - qy, dz1 = p1.z - qz;
                        float dd1 = fmaf(dx1, dx1, fmaf(dy1, dy1, dz1 * dz1));
                        ins3b(dd1, __float_as_int(p1.w), d0, d1, d2, i0, i1, i2);
                    }
                }
                ++p;
            }
        }

        // Butterfly merge of sorted triples across the 16-lane group.
        #pragma unroll
        for (int mask = 1; mask < LPQ; mask <<= 1) {
            const float e0 = __shfl_xor(d0, mask);
            const float e1 = __shfl_xor(d1, mask);
            const float e2 = __shfl_xor(d2, mask);
            const int   j0 = __shfl_xor(i0, mask);
            const int   j1 = __shfl_xor(i1, mask);
            const int   j2 = __shfl_xor(i2, mask);
            ins3b(e0, j0, d0, d1, d2, i0, i1, i2);
            ins3b(e1, j1, d0, d1, d2, i0, i1, i2);
            ins3b(e2, j2, d0, d1, d2, i0, i1, i2);
        }

        // Certificate: any unexamined point is at least rmin away.
        float rmin = 1e30f;
        if (lx > 0)      rmin = fminf(rmin, qx - (float)lx * cs);
        if (hx < GR - 1) rmin = fminf(rmin, (float)(hx + 1) * cs - qx);
        if (ly > 0)      rmin = fminf(rmin, qy - (float)ly * cs);
        if (hy < GR - 1) rmin = fminf(rmin, (float)(hy + 1) * cs - qy);
        if (lz > 0)      rmin = fminf(rmin, qz - (float)lz * cs);
        if (hz < GR - 1) rmin = fminf(rmin, (float)(hz + 1) * cs - qz);
        const float rmin2 = (rmin >= 1e30f) ? 1e30f : rmin * rmin;
        const bool full = (lx == 0 && ly == 0 && lz == 0 &&
                           hx == GR - 1 && hy == GR - 1 && hz == GR - 1);
        if (d2 <= rmin2 || full) break;
        ++r;   // rare: re-scan larger region from scratch (no duplicate inserts)
    }

    // Epilogue: softmax(-d) over the 3 NN, weighted feature gather.
    float w1 = expf(d0 - d1);
    float w2 = expf(d0 - d2);
    const float inv = 1.0f / (1.0f + w1 + w2);
    const float w0 = inv;
    w1 *= inv;
    w2 *= inv;
    const float* f0 = feat + (size_t)(i0 + c * NN) * DD;
    const float* f1 = feat + (size_t)(i1 + c * NN) * DD;
    const float* f2 = feat + (size_t)(i2 + c * NN) * DD;
    float* o = out + (size_t)mg * DD;
    o[t]       = w0 * f0[t]       + w1 * f1[t]       + w2 * f2[t];
    o[t + 16]  = w0 * f0[t + 16]  + w1 * f1[t + 16]  + w2 * f2[t + 16];
}

extern "C" void kernel_launch(void* const* d_in, const int* in_sizes, int n_in,
                              void* d_out, int out_size, void* d_ws, size_t ws_size,
                              hipStream_t stream) {
    const float* feat   = (const float*)d_in[0];   // points_feat [1, C*N, D] f32
    const float* verts  = (const float*)d_in[1];   // vertices    [C, N, 3]  f32
    const float* nverts = (const float*)d_in[2];   // new_vertices[C, M, 3]  f32
    float* outp = (float*)d_out;                   // [1, C*M, D] f32

    unsigned* cursor = (unsigned*)d_ws;                            // doubles as counts
    unsigned* starts = (unsigned*)((char*)d_ws + WS_STARTS);
    float4*   sorted = (float4*)((char*)d_ws + WS_SORTED);

    k_zero   <<<dim3(CC * NCELL / BLOCK), dim3(BLOCK), 0, stream>>>(cursor);
    k_count  <<<dim3(CC * NN / BLOCK),    dim3(BLOCK), 0, stream>>>(verts, cursor);
    k_scan   <<<dim3(CC),                 dim3(BLOCK), 0, stream>>>(cursor, starts);
    k_scatter<<<dim3(CC * NN / BLOCK),    dim3(BLOCK), 0, stream>>>(verts, cursor, sorted);
    k_query  <<<dim3(CC * MM * LPQ / BLOCK), dim3(BLOCK), 0, stream>>>(
        feat, nverts, starts, sorted, outp);
}

// Round 4
// 102.063 us; speedup vs baseline: 1.0939x; 1.0939x over previous
//
#include <hip/hip_runtime.h>
#include <math.h>

// Problem constants (fixed by setup_inputs).
#define CC 4
#define NN 4096                  // vertices per class (== queries per class)
#define MM 4096
#define DD 32
#define GR 16                    // grid resolution per axis
#define NCELL (GR * GR * GR)     // 4096 cells
#define BLOCK 256

// ws layout (bytes), all 16B-aligned:
//   vstarts u32[CC*(NCELL+1)]  @ 0        (65552 -> pad to 65568)
//   vsorted float4[CC*NN]      @ 65568    (262144)
//   qsorted float4[CC*MM]      @ 327712   (262144)
//   recs    32B * CC*MM        @ 589856   (524288)
#define WS_VSORTED 65568
#define WS_QSORTED (WS_VSORTED + 262144)
#define WS_RECS    (WS_QSORTED + 262144)

__device__ __forceinline__ int cellof(float x) {
    int c = (int)(x * (float)GR);
    return min(max(c, 0), GR - 1);
}

// Branchless sorted-insert of (d, j) into top-3 (d0<=d1<=d2). Strict <
// keeps earlier entries on ties (matches jax top_k tie-break).
__device__ __forceinline__ void ins3b(float d, int j,
                                      float& d0, float& d1, float& d2,
                                      int& i0, int& i1, int& i2) {
    bool l2 = d < d2, l1 = d < d1, l0 = d < d0;
    d2 = l1 ? d1 : (l2 ? d : d2);
    i2 = l1 ? i1 : (l2 ? j : i2);
    d1 = l0 ? d0 : (l1 ? d : d1);
    i1 = l0 ? i0 : (l1 ? j : i1);
    d0 = l0 ? d : d0;
    i0 = l0 ? j : i0;
}

// One block per (class, src): blocks 0..3 sort verts, 4..7 sort queries.
// LDS counting sort; points cached in LDS so global is read once.
__global__ __launch_bounds__(BLOCK) void k_build(
    const float* __restrict__ verts,      // [CC,NN,3]
    const float* __restrict__ nverts,     // [CC,MM,3]
    unsigned* __restrict__ vstarts,       // [CC][NCELL+1]
    float4* __restrict__ vsorted,         // [CC][NN]  {x,y,z,localIdx}
    float4* __restrict__ qsorted)         // [CC][MM]  {x,y,z,localIdx}
{
    __shared__ unsigned cnt[NCELL];       // 16 KB (counts, then cursor)
    __shared__ float4   spts[NN];         // 64 KB point cache
    __shared__ unsigned wsum[4];

    const int tid  = threadIdx.x;
    const bool isQ = blockIdx.x >= CC;
    const int c    = blockIdx.x & (CC - 1);
    const float* src = (isQ ? nverts : verts) + (size_t)c * NN * 3;

    for (int i = tid; i < NCELL; i += BLOCK) cnt[i] = 0u;
    __syncthreads();

    for (int i = tid; i < NN; i += BLOCK) {
        const float x = src[3 * i], y = src[3 * i + 1], z = src[3 * i + 2];
        spts[i] = make_float4(x, y, z, __int_as_float(i));
        const int cell = (cellof(x) * GR + cellof(y)) * GR + cellof(z);
        atomicAdd(&cnt[cell], 1u);
    }
    __syncthreads();

    // Exclusive prefix over 4096 counts; thread t owns cells [t*16, t*16+16).
    unsigned local[16], sum = 0;
    #pragma unroll
    for (int k = 0; k < 16; ++k) { local[k] = cnt[tid * 16 + k]; sum += local[k]; }
    unsigned incl = sum;
    #pragma unroll
    for (int off = 1; off < 64; off <<= 1) {
        unsigned v = __shfl_up(incl, off);
        if ((tid & 63) >= off) incl += v;
    }
    const int wid = tid >> 6;
    if ((tid & 63) == 63) wsum[wid] = incl;
    __syncthreads();
    unsigned wbase = 0;
    for (int w = 0; w < wid; ++w) wbase += wsum[w];
    unsigned base = wbase + incl - sum;

    unsigned* st = vstarts + c * (NCELL + 1);
    #pragma unroll
    for (int k = 0; k < 16; ++k) {
        if (!isQ) st[tid * 16 + k] = base;
        cnt[tid * 16 + k] = base;          // scatter cursor
        base += local[k];
    }
    if (!isQ && tid == BLOCK - 1) st[NCELL] = base;   // == NN
    __syncthreads();

    float4* dst = (isQ ? qsorted : vsorted) + (size_t)c * NN;
    for (int i = tid; i < NN; i += BLOCK) {
        const float4 p = spts[i];
        const int cell = (cellof(p.x) * GR + cellof(p.y)) * GR + cellof(p.z);
        const unsigned pos = atomicAdd(&cnt[cell], 1u);
        dst[pos] = p;
    }
}

// One query per lane; queries arrive cell-sorted so a wave's lanes scan
// nearly identical cells (uniform trip counts, L1-broadcast loads).
__global__ __launch_bounds__(64) void k_query(
    const float4* __restrict__ qsorted,   // [CC][MM]
    const unsigned* __restrict__ vstarts, // [CC][NCELL+1]
    const float4* __restrict__ vsorted,   // [CC][NN]
    float4* __restrict__ recs)            // [CC*MM][2] {d0,d1,d2,-},{i0,i1,i2,orig}
{
    const int slot = blockIdx.x * 64 + threadIdx.x;   // 0..CC*MM-1
    const int c = slot >> 12;

    const float4 q = qsorted[slot];
    const float qx = q.x, qy = q.y, qz = q.z;

    const unsigned* st = vstarts + c * (NCELL + 1);
    const float4* pts = vsorted + (size_t)c * NN;

    const int cx = cellof(qx), cy = cellof(qy), cz = cellof(qz);

    // Off-block 1.0 seeds (local idx = global - c*NN) for jax-faithful
    // behavior in the measure-zero degenerate case.
    const int offb = (c == 0) ? NN : (-c * NN);
    const float cs = 1.0f / (float)GR;

    float d0, d1, d2;
    int   i0, i1, i2;

    int r = 2;
    for (;;) {
        d0 = d1 = d2 = 1.0f;
        i0 = offb; i1 = offb + 1; i2 = offb + 2;

        const int lx = max(cx - r, 0), hx = min(cx + r, GR - 1);
        const int ly = max(cy - r, 0), hy = min(cy + r, GR - 1);
        const int lz = max(cz - r, 0), hz = min(cz + r, GR - 1);

        for (int px = lx; px <= hx; ++px) {
            for (int py = ly; py <= hy; ++py) {
                const int rb = (px * GR + py) * GR;
                const unsigned a = st[rb + lz];
                const unsigned b = st[rb + hz + 1];    // contiguous z-run
                for (unsigned s = a; s < b; s += 2) {
                    const float4 p0 = pts[s];
                    const bool h1 = (s + 1 < b);
                    const float4 p1 = pts[h1 ? s + 1 : s];
                    float dx = p0.x - qx, dy = p0.y - qy, dz = p0.z - qz;
                    const float dd0 = fmaf(dx, dx, fmaf(dy, dy, dz * dz));
                    ins3b(dd0, __float_as_int(p0.w), d0, d1, d2, i0, i1, i2);
                    dx = p1.x - qx; dy = p1.y - qy; dz = p1.z - qz;
                    float dd1 = fmaf(dx, dx, fmaf(dy, dy, dz * dz));
                    dd1 = h1 ? dd1 : 1e30f;
                    ins3b(dd1, __float_as_int(p1.w), d0, d1, d2, i0, i1, i2);
                }
            }
        }

        // Certificate: any unexamined point is at least rmin away.
        float rmin = 1e30f;
        if (lx > 0)      rmin = fminf(rmin, qx - (float)lx * cs);
        if (hx < GR - 1) rmin = fminf(rmin, (float)(hx + 1) * cs - qx);
        if (ly > 0)      rmin = fminf(rmin, qy - (float)ly * cs);
        if (hy < GR - 1) rmin = fminf(rmin, (float)(hy + 1) * cs - qy);
        if (lz > 0)      rmin = fminf(rmin, qz - (float)lz * cs);
        if (hz < GR - 1) rmin = fminf(rmin, (float)(hz + 1) * cs - qz);
        const bool full = (lx == 0 && ly == 0 && lz == 0 &&
                           hx == GR - 1 && hy == GR - 1 && hz == GR - 1);
        if (full || d2 <= rmin * rmin) break;
        ++r;   // essentially never (P ~ 3e-12 per query at r=2)
    }

    recs[slot * 2] = make_float4(d0, d1, d2, 0.0f);
    int4 iv;
    iv.x = i0; iv.y = i1; iv.z = i2; iv.w = __float_as_int(q.w);  // orig local idx
    ((int4*)recs)[slot * 2 + 1] = iv;
}

// Softmax + weighted feature gather; 8 lanes per query, float4 per lane.
__global__ __launch_bounds__(BLOCK) void k_out(
    const float4* __restrict__ feat4,     // [CC*NN][8] float4
    const float4* __restrict__ recs,
    float4* __restrict__ out4)            // [CC*MM][8] float4
{
    const int gid  = blockIdx.x * BLOCK + threadIdx.x;   // CC*MM*8 threads
    const int slot = gid >> 3;
    const int e    = gid & 7;
    const int c    = slot >> 12;

    const float4 dv = recs[slot * 2];
    const int4   iv = ((const int4*)recs)[slot * 2 + 1];

    float w1 = expf(dv.x - dv.y);
    float w2 = expf(dv.x - dv.z);
    const float inv = 1.0f / (1.0f + w1 + w2);
    const float w0 = inv;
    w1 *= inv; w2 *= inv;

    const float4 a = feat4[(size_t)(iv.x + c * NN) * 8 + e];
    const float4 b = feat4[(size_t)(iv.y + c * NN) * 8 + e];
    const float4 g = feat4[(size_t)(iv.z + c * NN) * 8 + e];
    float4 o;
    o.x = w0 * a.x + w1 * b.x + w2 * g.x;
    o.y = w0 * a.y + w1 * b.y + w2 * g.y;
    o.z = w0 * a.z + w1 * b.z + w2 * g.z;
    o.w = w0 * a.w + w1 * b.w + w2 * g.w;
    out4[((size_t)c * MM + (size_t)iv.w) * 8 + e] = o;
}

extern "C" void kernel_launch(void* const* d_in, const int* in_sizes, int n_in,
                              void* d_out, int out_size, void* d_ws, size_t ws_size,
                              hipStream_t stream) {
    const float* feat   = (const float*)d_in[0];   // points_feat [1, C*N, D] f32
    const float* verts  = (const float*)d_in[1];   // vertices    [C, N, 3]  f32
    const float* nverts = (const float*)d_in[2];   // new_vertices[C, M, 3]  f32
    float* outp = (float*)d_out;                   // [1, C*M, D] f32

    unsigned* vstarts = (unsigned*)d_ws;
    float4*   vsorted = (float4*)((char*)d_ws + WS_VSORTED);
    float4*   qsorted = (float4*)((char*)d_ws + WS_QSORTED);
    float4*   recs    = (float4*)((char*)d_ws + WS_RECS);

    k_build<<<dim3(2 * CC), dim3(BLOCK), 0, stream>>>(verts, nverts,
                                                      vstarts, vsorted, qsorted);
    k_query<<<dim3(CC * MM / 64), dim3(64), 0, stream>>>(qsorted, vstarts,
                                                         vsorted, recs);
    k_out<<<dim3(CC * MM * 8 / BLOCK), dim3(BLOCK), 0, stream>>>(
        (const float4*)feat, recs, (float4*)outp);
}

// Round 5
// 71.996 us; speedup vs baseline: 1.5507x; 1.4176x over previous
//
#include <hip/hip_runtime.h>
#include <math.h>

// Problem constants (fixed by setup_inputs).
#define CC 4
#define NN 4096                  // vertices per class (== queries per class)
#define MM 4096
#define DD 32
#define GR 8                     // grid resolution per axis
#define NCELL (GR * GR * GR)     // 512 cells
#define LPQ 8                    // lanes cooperating per query
#define BBLK 1024                // k_build block
#define QBLK 256                 // k_query block

// ws layout (bytes), 16B-aligned:
//   vstarts u32[CC*(NCELL+1)]  @ 0      (8208 -> pad 8224)
//   vsorted float4[CC*NN]      @ 8224   (262144)
//   qsorted float4[CC*MM]      @ 270368 (262144)
#define WS_VSORTED 8224
#define WS_QSORTED (WS_VSORTED + 262144)

__device__ __forceinline__ int cellof(float x) {
    int c = (int)(x * (float)GR);
    return min(max(c, 0), GR - 1);
}

// Branchless sorted-insert of (d, j) into top-3 (d0<=d1<=d2). Strict <
// keeps earlier entries on ties (matches jax top_k tie-break).
__device__ __forceinline__ void ins3b(float d, int j,
                                      float& d0, float& d1, float& d2,
                                      int& i0, int& i1, int& i2) {
    bool l2 = d < d2, l1 = d < d1, l0 = d < d0;
    d2 = l1 ? d1 : (l2 ? d : d2);
    i2 = l1 ? i1 : (l2 ? j : i2);
    d1 = l0 ? d0 : (l1 ? d : d1);
    i1 = l0 ? i0 : (l1 ? j : i1);
    d0 = l0 ? d : d0;
    i0 = l0 ? j : i0;
}

// One block per (class, src): blocks 0..3 sort verts, 4..7 sort queries.
// LDS counting sort, points cached in LDS (global read once).
__global__ __launch_bounds__(BBLK) void k_build(
    const float* __restrict__ verts,      // [CC,NN,3]
    const float* __restrict__ nverts,     // [CC,MM,3]
    unsigned* __restrict__ vstarts,       // [CC][NCELL+1]
    float4* __restrict__ vsorted,         // [CC][NN]  {x,y,z,localIdx}
    float4* __restrict__ qsorted)         // [CC][MM]  {x,y,z,localIdx}
{
    __shared__ unsigned cnt[NCELL];       // 2 KB (counts -> cursor)
    __shared__ float4   spts[NN];         // 64 KB point cache
    __shared__ unsigned wsum[BBLK / 64];

    const int tid  = threadIdx.x;
    const bool isQ = blockIdx.x >= CC;
    const int c    = blockIdx.x & (CC - 1);
    const float* src = (isQ ? nverts : verts) + (size_t)c * NN * 3;

    if (tid < NCELL) cnt[tid] = 0u;
    __syncthreads();

    for (int i = tid; i < NN; i += BBLK) {
        const float x = src[3 * i], y = src[3 * i + 1], z = src[3 * i + 2];
        spts[i] = make_float4(x, y, z, __int_as_float(i));
        const int cell = (cellof(x) * GR + cellof(y)) * GR + cellof(z);
        atomicAdd(&cnt[cell], 1u);
    }
    __syncthreads();

    // Exclusive prefix over 512 counts: thread t (<512) owns cell t.
    const int lane = tid & 63, wid = tid >> 6;
    unsigned own = (tid < NCELL) ? cnt[tid] : 0u;
    unsigned incl = own;
    #pragma unroll
    for (int off = 1; off < 64; off <<= 1) {
        unsigned v = __shfl_up(incl, off);
        if (lane >= off) incl += v;
    }
    if (lane == 63) wsum[wid] = incl;
    __syncthreads();
    unsigned wbase = 0;
    for (int w = 0; w < wid; ++w) wbase += wsum[w];
    const unsigned excl = wbase + incl - own;

    unsigned* st = vstarts + c * (NCELL + 1);
    if (tid < NCELL) {
        if (!isQ) st[tid] = excl;
        // note: each thread reads only its own cnt[tid] above, so this
        // overwrite has no cross-thread hazard.
        cnt[tid] = excl;                    // scatter cursor
        if (!isQ && tid == NCELL - 1) st[NCELL] = wbase + incl;   // == NN
    }
    __syncthreads();

    float4* dst = (isQ ? qsorted : vsorted) + (size_t)c * NN;
    for (int i = tid; i < NN; i += BBLK) {
        const float4 p = spts[i];
        const int cell = (cellof(p.x) * GR + cellof(p.y)) * GR + cellof(p.z);
        const unsigned pos = atomicAdd(&cnt[cell], 1u);
        dst[pos] = p;
    }
}

// 8 lanes per query; z-runs split across lanes (no redundant outer work).
// Queries arrive cell-sorted -> uniform trip counts + L1-broadcast loads.
// Fused epilogue: softmax + feature gather (lane t does float4 column t).
__global__ __launch_bounds__(QBLK) void k_query(
    const float4* __restrict__ feat4,     // [CC*NN][8] float4
    const float4* __restrict__ qsorted,   // [CC][MM]
    const unsigned* __restrict__ vstarts, // [CC][NCELL+1]
    const float4* __restrict__ vsorted,   // [CC][NN]
    float4* __restrict__ out4)            // [CC*MM][8] float4
{
    const int tid  = threadIdx.x;
    const int t    = tid & (LPQ - 1);
    const int slot = (blockIdx.x * QBLK + tid) >> 3;   // 0..CC*MM-1
    const int c    = slot >> 12;

    const float4 q = qsorted[slot];
    const float qx = q.x, qy = q.y, qz = q.z;

    const unsigned* st = vstarts + c * (NCELL + 1);
    const float4* pts = vsorted + (size_t)c * NN;

    const int cx = cellof(qx), cy = cellof(qy), cz = cellof(qz);
    const int offb = (c == 0) ? NN : (-c * NN);   // off-block 1.0 seed indices
    const float cs = 1.0f / (float)GR;

    float d0, d1, d2;
    int   i0, i1, i2;

    int r = 1;
    for (;;) {
        d0 = d1 = d2 = 1.0f;
        i0 = offb; i1 = offb + 1; i2 = offb + 2;

        const int lx = max(cx - r, 0), hx = min(cx + r, GR - 1);
        const int ly = max(cy - r, 0), hy = min(cy + r, GR - 1);
        const int lz = max(cz - r, 0), hz = min(cz + r, GR - 1);

        if (r == 1) {
            // Static 3x3 columns, prefetched range pairs (independent loads).
            unsigned aa[9], bb[9];
            #pragma unroll
            for (int k = 0; k < 9; ++k) {
                const int dx = k / 3 - 1, dy = k % 3 - 1;
                const int px = cx + dx, py = cy + dy;
                const bool ok = (px >= 0) & (px < GR) & (py >= 0) & (py < GR);
                const int rb = ok ? ((px * GR + py) * GR) : 0;   // safe addr
                const unsigned av = st[rb + lz];
                const unsigned bv = st[rb + hz + 1];
                aa[k] = av;
                bb[k] = ok ? bv : av;                            // empty if !ok
            }
            #pragma unroll
            for (int k = 0; k < 9; ++k) {
                for (unsigned s = aa[k] + t; s < bb[k]; s += 2 * LPQ) {
                    const unsigned s1 = s + LPQ;
                    const float4 p0 = pts[s];
                    const bool h1 = s1 < bb[k];
                    const float4 p1 = pts[h1 ? s1 : s];
                    float dx0 = p0.x - qx, dy0 = p0.y - qy, dz0 = p0.z - qz;
                    const float dd0 = fmaf(dx0, dx0, fmaf(dy0, dy0, dz0 * dz0));
                    ins3b(dd0, __float_as_int(p0.w), d0, d1, d2, i0, i1, i2);
                    float dx1 = p1.x - qx, dy1 = p1.y - qy, dz1 = p1.z - qz;
                    float dd1 = fmaf(dx1, dx1, fmaf(dy1, dy1, dz1 * dz1));
                    dd1 = h1 ? dd1 : 1e30f;
                    ins3b(dd1, __float_as_int(p1.w), d0, d1, d2, i0, i1, i2);
                }
            }
        } else {
            // Generic (essentially never taken; P ~ 1e-11 per query).
            for (int px = lx; px <= hx; ++px) {
                for (int py = ly; py <= hy; ++py) {
                    const int rb = (px * GR + py) * GR;
                    const unsigned a = st[rb + lz];
                    const unsigned b = st[rb + hz + 1];
                    for (unsigned s = a + t; s < b; s += LPQ) {
                        const float4 p = pts[s];
                        const float dx = p.x - qx, dy = p.y - qy, dz = p.z - qz;
                        const float dd = fmaf(dx, dx, fmaf(dy, dy, dz * dz));
                        ins3b(dd, __float_as_int(p.w), d0, d1, d2, i0, i1, i2);
                    }
                }
            }
        }

        // Merge sorted triples across the 8-lane group.
        #pragma unroll
        for (int mask = 1; mask < LPQ; mask <<= 1) {
            const float e0 = __shfl_xor(d0, mask);
            const float e1 = __shfl_xor(d1, mask);
            const float e2 = __shfl_xor(d2, mask);
            const int   j0 = __shfl_xor(i0, mask);
            const int   j1 = __shfl_xor(i1, mask);
            const int   j2 = __shfl_xor(i2, mask);
            ins3b(e0, j0, d0, d1, d2, i0, i1, i2);
            ins3b(e1, j1, d0, d1, d2, i0, i1, i2);
            ins3b(e2, j2, d0, d1, d2, i0, i1, i2);
        }

        // Certificate (identical across the group -> uniform branch).
        float rmin = 1e30f;
        if (lx > 0)      rmin = fminf(rmin, qx - (float)lx * cs);
        if (hx < GR - 1) rmin = fminf(rmin, (float)(hx + 1) * cs - qx);
        if (ly > 0)      rmin = fminf(rmin, qy - (float)ly * cs);
        if (hy < GR - 1) rmin = fminf(rmin, (float)(hy + 1) * cs - qy);
        if (lz > 0)      rmin = fminf(rmin, qz - (float)lz * cs);
        if (hz < GR - 1) rmin = fminf(rmin, (float)(hz + 1) * cs - qz);
        const bool full = (lx == 0 && ly == 0 && lz == 0 &&
                           hx == GR - 1 && hy == GR - 1 && hz == GR - 1);
        if (full || d2 <= rmin * rmin) break;
        ++r;   // group rescans from seeds together (no duplicate inserts)
    }

    // Fused epilogue: softmax(-d) + weighted feature gather.
    float w1 = expf(d0 - d1);
    float w2 = expf(d0 - d2);
    const float inv = 1.0f / (1.0f + w1 + w2);
    const float w0 = inv;
    w1 *= inv; w2 *= inv;

    const float4 a = feat4[(size_t)(i0 + c * NN) * 8 + t];
    const float4 b = feat4[(size_t)(i1 + c * NN) * 8 + t];
    const float4 g = feat4[(size_t)(i2 + c * NN) * 8 + t];
    float4 o;
    o.x = w0 * a.x + w1 * b.x + w2 * g.x;
    o.y = w0 * a.y + w1 * b.y + w2 * g.y;
    o.z = w0 * a.z + w1 * b.z + w2 * g.z;
    o.w = w0 * a.w + w1 * b.w + w2 * g.w;
    const int orig = __float_as_int(q.w);
    out4[((size_t)(c << 12) + (size_t)orig) * 8 + t] = o;
}

extern "C" void kernel_launch(void* const* d_in, const int* in_sizes, int n_in,
                              void* d_out, int out_size, void* d_ws, size_t ws_size,
                              hipStream_t stream) {
    const float* feat   = (const float*)d_in[0];   // points_feat [1, C*N, D] f32
    const float* verts  = (const float*)d_in[1];   // vertices    [C, N, 3]  f32
    const float* nverts = (const float*)d_in[2];   // new_vertices[C, M, 3]  f32
    float* outp = (float*)d_out;                   // [1, C*M, D] f32

    unsigned* vstarts = (unsigned*)d_ws;
    float4*   vsorted = (float4*)((char*)d_ws + WS_VSORTED);
    float4*   qsorted = (float4*)((char*)d_ws + WS_QSORTED);

    k_build<<<dim3(2 * CC), dim3(BBLK), 0, stream>>>(verts, nverts,
                                                     vstarts, vsorted, qsorted);
    k_query<<<dim3(CC * MM * LPQ / QBLK), dim3(QBLK), 0, stream>>>(
        (const float4*)feat, qsorted, vstarts, vsorted, (float4*)outp);
}

// Round 6
// 69.494 us; speedup vs baseline: 1.6066x; 1.0360x over previous
//
#include <hip/hip_runtime.h>
#include <math.h>

// Problem constants (fixed by setup_inputs).
#define CC 4
#define NN 4096                  // vertices per class (== queries per class)
#define MM 4096
#define DD 32
#define GR 10                    // grid resolution per axis
#define NCELL (GR * GR * GR)     // 1000 cells
#define LPQ 16                   // lanes cooperating per query
#define BBLK 1024                // k_build block
#define QBLK 256                 // k_query block

// ws layout (bytes), 16B-aligned:
//   vstarts u32[CC*(NCELL+1)]  @ 0      (16016 -> pad 16032)
//   vsorted float4[CC*NN]      @ 16032  (262144)
//   qsorted float4[CC*MM]      @ 278176 (262144)
#define WS_VSORTED 16032
#define WS_QSORTED (WS_VSORTED + 262144)

__device__ __forceinline__ int cellof(float x) {
    int c = (int)(x * (float)GR);
    return min(max(c, 0), GR - 1);
}

// Branchless sorted-insert of (d, j) into top-3 (d0<=d1<=d2). Strict <
// keeps earlier entries on ties (matches jax top_k tie-break).
__device__ __forceinline__ void ins3b(float d, int j,
                                      float& d0, float& d1, float& d2,
                                      int& i0, int& i1, int& i2) {
    bool l2 = d < d2, l1 = d < d1, l0 = d < d0;
    d2 = l1 ? d1 : (l2 ? d : d2);
    i2 = l1 ? i1 : (l2 ? j : i2);
    d1 = l0 ? d0 : (l1 ? d : d1);
    i1 = l0 ? i0 : (l1 ? j : i1);
    d0 = l0 ? d : d0;
    i0 = l0 ? j : i0;
}

// One block per (class, src): blocks 0..3 sort verts, 4..7 sort queries.
// Thread j owns points 4j..4j+3, loaded as 3 coalesced float4 and held in
// REGISTERS across the scan (no LDS point cache). LDS counting sort.
__global__ __launch_bounds__(BBLK) void k_build(
    const float* __restrict__ verts,      // [CC,NN,3]
    const float* __restrict__ nverts,     // [CC,MM,3]
    unsigned* __restrict__ vstarts,       // [CC][NCELL+1]
    float4* __restrict__ vsorted,         // [CC][NN]  {x,y,z,localIdx}
    float4* __restrict__ qsorted)         // [CC][MM]  {x,y,z,localIdx}
{
    __shared__ unsigned cnt[NCELL];       // counts -> cursor
    __shared__ unsigned wsum[BBLK / 64];

    const int tid  = threadIdx.x;
    const bool isQ = blockIdx.x >= CC;
    const int c    = blockIdx.x & (CC - 1);
    const float4* src4 =
        (const float4*)((isQ ? nverts : verts) + (size_t)c * NN * 3);

    if (tid < NCELL) cnt[tid] = 0u;
    __syncthreads();

    // One load round: 3 independent dwordx4 -> 4 points in registers.
    const float4 fa = src4[3 * tid];
    const float4 fb = src4[3 * tid + 1];
    const float4 fc = src4[3 * tid + 2];
    const float px[4] = {fa.x, fa.w, fb.z, fc.y};
    const float py[4] = {fa.y, fb.x, fb.w, fc.z};
    const float pz[4] = {fa.z, fb.y, fc.x, fc.w};
    int cell[4];
    #pragma unroll
    for (int u = 0; u < 4; ++u) {
        cell[u] = (cellof(px[u]) * GR + cellof(py[u])) * GR + cellof(pz[u]);
        atomicAdd(&cnt[cell[u]], 1u);
    }
    __syncthreads();

    // Exclusive prefix over 1000 counts: thread t (<NCELL) owns cell t.
    const int lane = tid & 63, wid = tid >> 6;
    const unsigned own = (tid < NCELL) ? cnt[tid] : 0u;
    unsigned incl = own;
    #pragma unroll
    for (int off = 1; off < 64; off <<= 1) {
        unsigned v = __shfl_up(incl, off);
        if (lane >= off) incl += v;
    }
    if (lane == 63) wsum[wid] = incl;
    __syncthreads();
    unsigned wbase = 0;
    for (int w = 0; w < wid; ++w) wbase += wsum[w];
    const unsigned excl = wbase + incl - own;

    unsigned* st = vstarts + c * (NCELL + 1);
    if (tid < NCELL) {
        if (!isQ) st[tid] = excl;
        cnt[tid] = excl;                     // scatter cursor (own-slot only)
        if (!isQ && tid == NCELL - 1) st[NCELL] = wbase + incl;   // == NN
    }
    __syncthreads();

    float4* dst = (isQ ? qsorted : vsorted) + (size_t)c * NN;
    #pragma unroll
    for (int u = 0; u < 4; ++u) {
        const unsigned pos = atomicAdd(&cnt[cell[u]], 1u);
        dst[pos] = make_float4(px[u], py[u], pz[u],
                               __int_as_float(4 * tid + u));
    }
}

// 16 lanes per query; all 18 point loads of the 3x3 column neighborhood are
// issued as ONE predicated batch (single memory round-trip). Queries arrive
// cell-sorted -> coherent trip counts + L1-friendly addresses. Fused
// softmax + feature gather epilogue (lane t does float2 column t).
__global__ __launch_bounds__(QBLK) void k_query(
    const float2* __restrict__ feat2,     // [CC*NN][16] float2
    const float4* __restrict__ qsorted,   // [CC][MM]
    const unsigned* __restrict__ vstarts, // [CC][NCELL+1]
    const float4* __restrict__ vsorted,   // [CC][NN]
    float2* __restrict__ out2)            // [CC*MM][16] float2
{
    const int tid  = threadIdx.x;
    const int t    = tid & (LPQ - 1);
    const int slot = (blockIdx.x * QBLK + tid) >> 4;   // 0..CC*MM-1
    const int c    = slot >> 12;

    const float4 q = qsorted[slot];
    const float qx = q.x, qy = q.y, qz = q.z;

    const unsigned* st = vstarts + c * (NCELL + 1);
    const float4* pts = vsorted + (size_t)c * NN;

    const int cx = cellof(qx), cy = cellof(qy), cz = cellof(qz);
    const int offb = (c == 0) ? NN : (-c * NN);   // off-block 1.0 seed indices
    const float cs = 1.0f / (float)GR;

    float d0 = 1.0f, d1 = 1.0f, d2 = 1.0f;
    int   i0 = offb, i1 = offb + 1, i2 = offb + 2;

    // ---- r=1 fast path: fully unrolled predicated batch ----
    {
        const int lz = max(cz - 1, 0), hz = min(cz + 1, GR - 1);
        unsigned aa[9], bb[9];
        #pragma unroll
        for (int k = 0; k < 9; ++k) {
            const int px = cx + k / 3 - 1, py = cy + k % 3 - 1;
            const bool ok = (px >= 0) & (px < GR) & (py >= 0) & (py < GR);
            const int rb = ok ? ((px * GR + py) * GR) : 0;   // safe addr
            const unsigned av = st[rb + lz];
            const unsigned bv = st[rb + hz + 1];
            aa[k] = av;
            bb[k] = ok ? bv : av;                            // empty if !ok
        }
        // Issue all 18 point loads (independent; clamped addresses).
        float4 P0[9], P1[9];
        #pragma unroll
        for (int k = 0; k < 9; ++k) {
            const unsigned s0 = aa[k] + t, s1 = s0 + LPQ;
            P0[k] = pts[s0 < bb[k] ? s0 : 0u];
            P1[k] = pts[s1 < bb[k] ? s1 : 0u];
        }
        unsigned over = 0u;
        #pragma unroll
        for (int k = 0; k < 9; ++k) {
            const unsigned s0 = aa[k] + t, s1 = s0 + LPQ;
            float dx = P0[k].x - qx, dy = P0[k].y - qy, dz = P0[k].z - qz;
            float dd = fmaf(dx, dx, fmaf(dy, dy, dz * dz));
            dd = (s0 < bb[k]) ? dd : 1e30f;
            ins3b(dd, __float_as_int(P0[k].w), d0, d1, d2, i0, i1, i2);
            dx = P1[k].x - qx; dy = P1[k].y - qy; dz = P1[k].z - qz;
            float de = fmaf(dx, dx, fmaf(dy, dy, dz * dz));
            de = (s1 < bb[k]) ? de : 1e30f;
            ins3b(de, __float_as_int(P1[k].w), d0, d1, d2, i0, i1, i2);
            over |= (bb[k] - aa[k] > 2u * LPQ) ? 1u : 0u;
        }
        if (over) {   // P ~ 1e-6 per query: columns longer than 32 pts
            #pragma unroll 1
            for (int k = 0; k < 9; ++k) {
                for (unsigned s = aa[k] + 2u * LPQ + t; s < bb[k]; s += LPQ) {
                    const float4 p = pts[s];
                    const float dx = p.x - qx, dy = p.y - qy, dz = p.z - qz;
                    const float dd = fmaf(dx, dx, fmaf(dy, dy, dz * dz));
                    ins3b(dd, __float_as_int(p.w), d0, d1, d2, i0, i1, i2);
                }
            }
        }
    }

    // Merge sorted triples across the 16-lane group.
    #pragma unroll
    for (int mask = 1; mask < LPQ; mask <<= 1) {
        const float e0 = __shfl_xor(d0, mask);
        const float e1 = __shfl_xor(d1, mask);
        const float e2 = __shfl_xor(d2, mask);
        const int   j0 = __shfl_xor(i0, mask);
        const int   j1 = __shfl_xor(i1, mask);
        const int   j2 = __shfl_xor(i2, mask);
        ins3b(e0, j0, d0, d1, d2, i0, i1, i2);
        ins3b(e1, j1, d0, d1, d2, i0, i1, i2);
        ins3b(e2, j2, d0, d1, d2, i0, i1, i2);
    }

    // Certificate for r=1 (group-uniform). Any unexamined point >= rmin away.
    {
        const int lx = max(cx - 1, 0), hx = min(cx + 1, GR - 1);
        const int ly = max(cy - 1, 0), hy = min(cy + 1, GR - 1);
        const int lz = max(cz - 1, 0), hz = min(cz + 1, GR - 1);
        float rmin = 1e30f;
        if (lx > 0)      rmin = fminf(rmin, qx - (float)lx * cs);
        if (hx < GR - 1) rmin = fminf(rmin, (float)(hx + 1) * cs - qx);
        if (ly > 0)      rmin = fminf(rmin, qy - (float)ly * cs);
        if (hy < GR - 1) rmin = fminf(rmin, (float)(hy + 1) * cs - qy);
        if (lz > 0)      rmin = fminf(rmin, qz - (float)lz * cs);
        if (hz < GR - 1) rmin = fminf(rmin, (float)(hz + 1) * cs - qz);

        if (!(d2 <= rmin * rmin)) {
            // Rare retry (P ~ 5.8e-6/query): generic expanding rescan.
            for (int r = 2;; ++r) {
                d0 = d1 = d2 = 1.0f;
                i0 = offb; i1 = offb + 1; i2 = offb + 2;
                const int Lx = max(cx - r, 0), Hx = min(cx + r, GR - 1);
                const int Ly = max(cy - r, 0), Hy = min(cy + r, GR - 1);
                const int Lz = max(cz - r, 0), Hz = min(cz + r, GR - 1);
                for (int px = Lx; px <= Hx; ++px) {
                    for (int py = Ly; py <= Hy; ++py) {
                        const int rb = (px * GR + py) * GR;
                        const unsigned a = st[rb + Lz];
                        const unsigned b = st[rb + Hz + 1];
                        for (unsigned s = a + t; s < b; s += LPQ) {
                            const float4 p = pts[s];
                            const float dx = p.x - qx, dy = p.y - qy,
                                        dz = p.z - qz;
                            const float dd =
                                fmaf(dx, dx, fmaf(dy, dy, dz * dz));
                            ins3b(dd, __float_as_int(p.w),
                                  d0, d1, d2, i0, i1, i2);
                        }
                    }
                }
                #pragma unroll
                for (int mask = 1; mask < LPQ; mask <<= 1) {
                    const float e0 = __shfl_xor(d0, mask);
                    const float e1 = __shfl_xor(d1, mask);
                    const float e2 = __shfl_xor(d2, mask);
                    const int   j0 = __shfl_xor(i0, mask);
                    const int   j1 = __shfl_xor(i1, mask);
                    const int   j2 = __shfl_xor(i2, mask);
                    ins3b(e0, j0, d0, d1, d2, i0, i1, i2);
                    ins3b(e1, j1, d0, d1, d2, i0, i1, i2);
                    ins3b(e2, j2, d0, d1, d2, i0, i1, i2);
                }
                float rm = 1e30f;
                if (Lx > 0)      rm = fminf(rm, qx - (float)Lx * cs);
                if (Hx < GR - 1) rm = fminf(rm, (float)(Hx + 1) * cs - qx);
                if (Ly > 0)      rm = fminf(rm, qy - (float)Ly * cs);
                if (Hy < GR - 1) rm = fminf(rm, (float)(Hy + 1) * cs - qy);
                if (Lz > 0)      rm = fminf(rm, qz - (float)Lz * cs);
                if (Hz < GR - 1) rm = fminf(rm, (float)(Hz + 1) * cs - qz);
                const bool full = (Lx == 0 && Ly == 0 && Lz == 0 &&
                                   Hx == GR - 1 && Hy == GR - 1 &&
                                   Hz == GR - 1);
                if (full || d2 <= rm * rm) break;
            }
        }
    }

    // Fused epilogue: softmax(-d) + weighted feature gather (float2/lane).
    float w1 = expf(d0 - d1);
    float w2 = expf(d0 - d2);
    const float inv = 1.0f / (1.0f + w1 + w2);
    const float w0 = inv;
    w1 *= inv; w2 *= inv;

    const float2 a = feat2[(size_t)(i0 + c * NN) * 16 + t];
    const float2 b = feat2[(size_t)(i1 + c * NN) * 16 + t];
    const float2 g = feat2[(size_t)(i2 + c * NN) * 16 + t];
    float2 o;
    o.x = w0 * a.x + w1 * b.x + w2 * g.x;
    o.y = w0 * a.y + w1 * b.y + w2 * g.y;
    const int orig = __float_as_int(q.w);
    out2[((size_t)(c << 12) + (size_t)orig) * 16 + t] = o;
}

extern "C" void kernel_launch(void* const* d_in, const int* in_sizes, int n_in,
                              void* d_out, int out_size, void* d_ws, size_t ws_size,
                              hipStream_t stream) {
    const float* feat   = (const float*)d_in[0];   // points_feat [1, C*N, D] f32
    const float* verts  = (const float*)d_in[1];   // vertices    [C, N, 3]  f32
    const float* nverts = (const float*)d_in[2];   // new_vertices[C, M, 3]  f32
    float* outp = (float*)d_out;                   // [1, C*M, D] f32

    unsigned* vstarts = (unsigned*)d_ws;
    float4*   vsorted = (float4*)((char*)d_ws + WS_VSORTED);
    float4*   qsorted = (float4*)((char*)d_ws + WS_QSORTED);

    k_build<<<dim3(2 * CC), dim3(BBLK), 0, stream>>>(verts, nverts,
                                                     vstarts, vsorted, qsorted);
    k_query<<<dim3(CC * MM * LPQ / QBLK), dim3(QBLK), 0, stream>>>(
        (const float2*)feat, qsorted, vstarts, vsorted, (float2*)outp);
}